// Round 14
// baseline (204.202 us; speedup 1.0000x reference)
//
#include <hip/hip_runtime.h>
#include <stdint.h>

// B=2, CIN=256, COUT=256, H=W=128, K=3, G=4
#define HW    16384
#define CIN   256
#define COUT  256
#define Hh    128
#define Ww    128
#define OFFC  72        // G*2*K*K

typedef __attribute__((ext_vector_type(4))) float    f32x4;
typedef __attribute__((ext_vector_type(2))) _Float16 f16x2;
typedef __attribute__((ext_vector_type(8))) _Float16 f16x8;
typedef unsigned short u16;
typedef unsigned int   u32;

__device__ __forceinline__ u16 f2h(float f) { return __builtin_bit_cast(u16, (_Float16)f); }
__device__ __forceinline__ u32 pk2(float f) { u32 h = f2h(f); return h | (h << 16); }
__device__ __forceinline__ f16x2 bch(u32 u) { return __builtin_bit_cast(f16x2, u); }

// ---------------------------------------------------------------------------
// KPREP (R5 version, kept): lean skew-rotated LDS transpose.
// ---------------------------------------------------------------------------
__global__ __launch_bounds__(256) void kprep(const float* __restrict__ x, const float* __restrict__ wd,
                                             const float* __restrict__ wo, u16* __restrict__ xt,
                                             u16* __restrict__ wfrag, u16* __restrict__ wfrag2) {
  __shared__ float smem[8 * 576];               // 18 KB; transpose uses 9.2 KB as u32
  int blk = blockIdx.x;
  if (blk < 2048) {                             // ---- transpose to NHWC f16, 64 px ----
    int bg = blk >> 8;
    int p0 = (blk & 255) << 6;
    int pq = threadIdx.x & 15;                  // px quad: px = pq*4..+3
    int cs = threadIdx.x >> 4;                  // cpair seed 0..15
    const float* src = x + (size_t)bg * 64 * HW + p0 + pq * 4;
    u32* lds = (u32*)smem;                      // [px][36], col skew-rotated by px
    #pragma unroll
    for (int s = 0; s < 2; ++s) {
      int c2 = cs + 16 * s;                     // cpair index 0..31 (ch 2c2, 2c2+1)
      f32x4 lo = *(const f32x4*)(src + (size_t)(2 * c2 + 0) * HW);
      f32x4 hi = *(const f32x4*)(src + (size_t)(2 * c2 + 1) * HW);
      #pragma unroll
      for (int j = 0; j < 4; ++j) {
        int px = pq * 4 + j;
        u32 pkv = (u32)f2h(lo[j]) | ((u32)f2h(hi[j]) << 16);
        lds[px * 36 + ((c2 + px) & 31)] = pkv;  // skew: 2-way max
      }
    }
    __syncthreads();
    u16* dstb = xt + ((size_t)bg * HW + p0) * 64;
    #pragma unroll
    for (int r = 0; r < 2; ++r) {
      int e  = r * 256 + threadIdx.x;           // 0..511
      int px = e >> 3, c4 = e & 7;              // cpairs 4c4..4c4+3
      u32 w[4];
      #pragma unroll
      for (int m = 0; m < 4; ++m)
        w[m] = lds[px * 36 + ((4 * c4 + m + px) & 31)];
      *(uint4*)(dstb + (size_t)e * 8) = make_uint4(w[0], w[1], w[2], w[3]);
    }
  } else if (blk < 2176) {                      // ---- w_deform prepack (8 couts) ----
    int bb = blk - 2048;                        // 0..127
    int nh = bb & 31;                           // couts [nh*8, nh*8+8)
    int g  = bb >> 5;
    const float* src = wd + (size_t)(nh * 8) * 2304 + (size_t)g * 64 * 9;
    #pragma unroll
    for (int r = 0; r < 18; ++r) {
      int idx = threadIdx.x + 256 * r;          // 0..4607
      int cl  = idx / 576;
      int rem = idx - cl * 576;
      smem[cl * 576 + rem] = src[(size_t)cl * 2304 + rem];
    }
    __syncthreads();
    int nt = nh >> 1, nb = (nh & 1) * 8;
    #pragma unroll
    for (int r = 0; r < 18; ++r) {
      int o  = threadIdx.x + 256 * r;           // 0..4607
      int j  = o & 7;
      int n8 = (o >> 3) & 7;
      int q  = (o >> 6) & 3;
      int kcl = o >> 8;                         // t*2+half
      int t = kcl >> 1, half = kcl & 1;
      int cg = half * 32 + q * 8 + j;
      float v = smem[n8 * 576 + cg * 9 + t];
      int kc = (g * 9 + t) * 2 + half;
      int lane = q * 16 + nb + n8;
      wfrag[((size_t)(kc * 16 + nt) * 64 + lane) * 8 + j] = f2h(v);
    }
  } else {                                      // ---- w_offset prepack ----
    int e = (blk - 2176) * 256 + threadIdx.x;   // < 20480
    int j = e & 7;
    int lane = (e >> 3) & 63;
    int idx = e >> 9;
    int kc = idx / 5, nt = idx - 5 * kc;
    int n16 = lane & 15, q = lane >> 4;
    int oc = nt * 16 + n16;
    int c  = kc * 32 + q * 8 + j;
    float v = (oc < OFFC) ? wo[(size_t)oc * CIN + c] : 0.f;
    wfrag2[e] = f2h(v);
  }
}

// ---------------------------------------------------------------------------
// K2 (R14 = R8 base + consume RETILE 32px x 64cout):
//   Ablation (R12): consume-alone 29 us dominated by 256 KB/tap LDS A-reads
//   (every wave re-read the whole A-tile for its skinny 128px x 16cout slice).
//   Retile: wave wv -> px-block P = wv&3 (subtiles 2P,2P+1), cout-block
//   C = wv>>2 (nt 4C..4C+3). Per tap: 4 A ds_reads (4 KB, was 16) + 8 B
//   uint4 loads (4-way L1-shared across the 4 waves of a C-group) + 16 MFMA
//   (unchanged). LDS A-traffic/CU/tap: 256 -> 64 KB. Producer side, offl,
//   gathers, barriers, swizzle: byte-identical to R8 (passing, 100.6 us).
//   R13's 3-slot ring reverted (regressed, spill fingerprints).
// ---------------------------------------------------------------------------
__device__ __forceinline__ void mkpre(float yy, float xx, int* ob, u32* wp) {
  float y0f = floorf(yy), x0f = floorf(xx);
  float fy = yy - y0f, fx = xx - x0f;
  int y0 = (int)y0f, x0 = (int)x0f;
  int y1 = y0 + 1, x1 = x0 + 1;
  float vy0 = (y0 >= 0 && y0 < Hh) ? 1.f : 0.f;
  float vy1 = (y1 >= 0 && y1 < Hh) ? 1.f : 0.f;
  float vx0 = (x0 >= 0 && x0 < Ww) ? 1.f : 0.f;
  float vx1 = (x1 >= 0 && x1 < Ww) ? 1.f : 0.f;
  wp[0] = pk2((1.f - fy) * (1.f - fx) * vy0 * vx0);   // zero-pad folded into weights
  wp[1] = pk2((1.f - fy) * fx * vy0 * vx1);
  wp[2] = pk2(fy * (1.f - fx) * vy1 * vx0);
  wp[3] = pk2(fy * fx * vy1 * vx1);
  int cy0 = min(max(y0, 0), Hh - 1), cy1 = min(max(y1, 0), Hh - 1);
  int cx0 = min(max(x0, 0), Ww - 1), cx1 = min(max(x1, 0), Ww - 1);
  ob[0] = (cy0 * Ww + cx0) << 7;                // byte offsets, 128 B pixel records
  ob[1] = (cy0 * Ww + cx1) << 7;
  ob[2] = (cy1 * Ww + cx0) << 7;
  ob[3] = (cy1 * Ww + cx1) << 7;
}

__device__ __forceinline__ uint4 bil16(const uint4* v, const u32* wp) {
  f16x2 W0 = bch(wp[0]), W1 = bch(wp[1]), W2 = bch(wp[2]), W3 = bch(wp[3]);
  uint4 r;
  { f16x2 s = bch(v[0].x) * W0 + bch(v[1].x) * W1 + bch(v[2].x) * W2 + bch(v[3].x) * W3; r.x = __builtin_bit_cast(u32, s); }
  { f16x2 s = bch(v[0].y) * W0 + bch(v[1].y) * W1 + bch(v[2].y) * W2 + bch(v[3].y) * W3; r.y = __builtin_bit_cast(u32, s); }
  { f16x2 s = bch(v[0].z) * W0 + bch(v[1].z) * W1 + bch(v[2].z) * W2 + bch(v[3].z) * W3; r.z = __builtin_bit_cast(u32, s); }
  { f16x2 s = bch(v[0].w) * W0 + bch(v[1].w) * W1 + bch(v[2].w) * W2 + bch(v[3].w) * W3; r.w = __builtin_bit_cast(u32, s); }
  return r;
}

__global__ __launch_bounds__(1024, 4) void k2(const u16* __restrict__ xt, const u16* __restrict__ wfrag2,
                                              const float* __restrict__ bo, const u16* __restrict__ wfrag,
                                              float* __restrict__ out) {
  __shared__ u16   astage[2 * 16 * 512];        // [buf][sp8*hp2][lane][8] = 32 KB
  __shared__ float offl[128 * 74];              // [px][oc] stride-74, 37.9 KB
  int tid  = threadIdx.x;
  int lane = tid & 63, n16 = lane & 15, q = (tid >> 4) & 3;
  int wv   = tid >> 6;                          // 0..15
  int sp   = wv >> 1;                           // produced px subtile (8)
  int hp   = wv & 1;                            // produced 32-ch half
  int P    = wv & 3;                            // consumed px-block (32 px)
  int C    = wv >> 2;                           // consumed cout-block (64 couts)
  int blk  = blockIdx.x;
  int swz  = (blk & 7) * 32 + (blk >> 3);       // bijective XCD swizzle (256%8==0)
  int b  = swz >> 7;
  int p0 = (swz & 127) << 7;                    // 128-px tile = one image row
  int h  = p0 >> 7;
  const char* xtb = (const char*)xt + (size_t)b * 4 * HW * 128;
  float fh  = (float)h;
  float fxp = (float)(sp * 16 + n16);           // producer-pixel x (w0 == 0)
  int   chb = hp * 64 + q * 16;                 // byte offset within 128 B record
  int   pxl = sp * 16 + n16;

  f32x4 acc[2][4];                              // [px-subtile m][cout nt i]
  #pragma unroll
  for (int m = 0; m < 2; ++m)
    #pragma unroll
    for (int i = 0; i < 4; ++i) acc[m][i] = (f32x4){0.f, 0.f, 0.f, 0.f};

  // ---- phase 0: waves 0-7 compute offset conv (128 px x 72 oc) -> offl ----
  if (wv < 8) {
    f32x4 oacc[5];
    #pragma unroll
    for (int nt = 0; nt < 5; ++nt) {
      int oc = nt * 16 + n16;
      float bv = (oc < OFFC) ? bo[oc] : 0.f;
      oacc[nt] = (f32x4){bv, bv, bv, bv};
    }
    #pragma unroll
    for (int kc = 0; kc < 8; ++kc) {
      int g = kc >> 1;
      f16x8 af = __builtin_bit_cast(f16x8, *(const uint4*)(xtb +
          ((size_t)(g * HW + p0 + wv * 16 + n16)) * 128 + (kc & 1) * 64 + q * 16));
      #pragma unroll
      for (int nt = 0; nt < 5; ++nt) {
        f16x8 bfo = __builtin_bit_cast(f16x8, *(const uint4*)(wfrag2 + (size_t)(((kc * 5 + nt) << 6) + lane) * 8));
        oacc[nt] = __builtin_amdgcn_mfma_f32_16x16x32_f16(af, bfo, oacc[nt], 0, 0, 0);
      }
    }
    #pragma unroll
    for (int nt = 0; nt < 5; ++nt) {
      int oc = nt * 16 + n16;
      if (oc < OFFC) {
        #pragma unroll
        for (int r = 0; r < 4; ++r)
          offl[(wv * 16 + q * 4 + r) * 74 + oc] = oacc[nt][r];
      }
    }
  }
  __syncthreads();                              // offl ready

  uint4 dA[4], dB[4];                           // ping-pong gather sets (const-indexed)
  u32   wpA[4], wpB[4];

  auto issue = [&](int gt, uint4* dd, u32* wpp) {
    float oy = offl[pxl * 74 + gt * 2];
    float ox = offl[pxl * 74 + gt * 2 + 1];
    int g = (gt * 57) >> 9;                     // gt/9
    int t = gt - g * 9;
    int i = (t * 683) >> 11;                    // t/3
    int j = t - i * 3;
    int ob[4];
    mkpre(fh + (float)(i - 1) + oy, fxp + (float)(j - 1) + ox, ob, wpp);
    const char* xg = xtb + (size_t)g * HW * 128;
    #pragma unroll
    for (int c = 0; c < 4; ++c)
      dd[c] = *(const uint4*)(xg + ob[c] + chb);
  };
  // consume tap gt from astage[slot]: 8 B loads (in-consume, 4-way L1 reuse
  // across the C-group), 4 A ds_reads, 16 MFMA. slot literal at call sites.
  auto consume = [&](int slot, int gt) {
    const u16* wb = wfrag + ((size_t)((2 * gt) * 16 + 4 * C) * 64 + lane) * 8;
    uint4 bf0[4], bf1[4];
    #pragma unroll
    for (int i = 0; i < 4; ++i) {
      bf0[i] = *(const uint4*)(wb + i * 512);          // kc=2gt,   nt=4C+i
      bf1[i] = *(const uint4*)(wb + 8192 + i * 512);   // kc=2gt+1, nt=4C+i
    }
    #pragma unroll
    for (int m = 0; m < 2; ++m) {
      f16x8 af0 = __builtin_bit_cast(f16x8,
          *(const uint4*)&astage[(slot * 16 + (2 * P + m) * 2 + 0) * 512 + lane * 8]);
      #pragma unroll
      for (int i = 0; i < 4; ++i)
        acc[m][i] = __builtin_amdgcn_mfma_f32_16x16x32_f16(af0, __builtin_bit_cast(f16x8, bf0[i]), acc[m][i], 0, 0, 0);
      f16x8 af1 = __builtin_bit_cast(f16x8,
          *(const uint4*)&astage[(slot * 16 + (2 * P + m) * 2 + 1) * 512 + lane * 8]);
      #pragma unroll
      for (int i = 0; i < 4; ++i)
        acc[m][i] = __builtin_amdgcn_mfma_f32_16x16x32_f16(af1, __builtin_bit_cast(f16x8, bf1[i]), acc[m][i], 0, 0, 0);
    }
  };

  // ---- prologue: gt=0 -> dA, gt=1 -> dB, produce slot0 from dA ----
  issue(0, dA, wpA);
  issue(1, dB, wpB);
  *(uint4*)&astage[(0 * 16 + sp * 2 + hp) * 512 + lane * 8] = bil16(dA, wpA);
  __syncthreads();                              // slot0 ready

  // ---- main loop, x2 unrolled: one barrier per tap (R8 cadence) ----
  #pragma unroll 1
  for (int gt = 0; gt < 36; gt += 2) {
    // even gt: stage gt+1 (dB) -> slot1; issue gt+2; consume slot0
    *(uint4*)&astage[(1 * 16 + sp * 2 + hp) * 512 + lane * 8] = bil16(dB, wpB);
    if (gt + 2 < 36) issue(gt + 2, dA, wpA);
    consume(0, gt);
    __syncthreads();
    // odd gt+1: stage gt+2 (dA) -> slot0; issue gt+3; consume slot1
    if (gt + 2 < 36) {
      *(uint4*)&astage[(0 * 16 + sp * 2 + hp) * 512 + lane * 8] = bil16(dA, wpA);
      issue(gt + 3, dB, wpB);                   // gt+3 <= 35 here (gt <= 32)
    }
    consume(1, gt + 1);
    __syncthreads();
  }

  // ---- epilogue: px = p0 + P*32 + m*16 + q*4 + r, cout = C*64 + i*16 + n16 ----
  float* op = out + (size_t)b * COUT * HW + p0 + P * 32;
  #pragma unroll
  for (int m = 0; m < 2; ++m)
    #pragma unroll
    for (int i = 0; i < 4; ++i) {
      f32x4 v = acc[m][i];
      #pragma unroll
      for (int r = 0; r < 4; ++r) v[r] = fmaxf(v[r], 0.f);
      int cout = C * 64 + i * 16 + n16;
      *(f32x4*)(op + (size_t)cout * HW + m * 16 + q * 4) = v;
    }
}

// ---------------------------------------------------------------------------
extern "C" void kernel_launch(void* const* d_in, const int* in_sizes, int n_in,
                              void* d_out, int out_size, void* d_ws, size_t ws_size,
                              hipStream_t stream) {
  const float* x  = (const float*)d_in[0];
  const float* wo = (const float*)d_in[1];
  const float* bo = (const float*)d_in[2];
  const float* wd = (const float*)d_in[3];
  float* out = (float*)d_out;

  // ws: xt 16,777,216 | wfrag 1,179,648 | wfrag2 40,960
  u16* xtp    = (u16*)d_ws;
  u16* wfrag  = (u16*)((char*)d_ws + 16777216);
  u16* wfrag2 = (u16*)((char*)d_ws + 16777216 + 1179648);

  kprep<<<2256, 256, 0, stream>>>(x, wd, wo, xtp, wfrag, wfrag2);
  k2   <<<256, 1024, 0, stream>>>(xtp, wfrag2, bo, wfrag, out);
}

// Round 15
// 175.368 us; speedup vs baseline: 1.1644x; 1.1644x over previous
//
#include <hip/hip_runtime.h>
#include <stdint.h>

// FINAL (restore of R8 -- best measured: k2 100.6 us, total 176.7 us).
// Session summary: R8's structure (128-px tile, 16 waves, 1 blk/CU,
// producer/consumer LDS A-exchange, 1-phase gather+B prefetch, __syncthreads,
// XCD swizzle) is the empirical floor. Falsified beyond it: nodrain barriers
// (R1/R4), barrier count (R6), barrier domains (R3), L2/HBM locality
// (R3/R5), B-prefetch depth (R4/R13), L1 sector pressure (R8 vs R5),
// intra-phase lockstep (R9/R10), LDS A-read amplification (R14).
// R12 ablation: consume-alone 29 us (MfmaUtil 58%), feed-alone 17 us;
// the remaining 2.2x combined-mode interference resisted all remedies.
// B=2, CIN=256, COUT=256, H=W=128, K=3, G=4
#define HW    16384
#define CIN   256
#define COUT  256
#define Hh    128
#define Ww    128
#define OFFC  72        // G*2*K*K

typedef __attribute__((ext_vector_type(4))) float    f32x4;
typedef __attribute__((ext_vector_type(2))) _Float16 f16x2;
typedef __attribute__((ext_vector_type(8))) _Float16 f16x8;
typedef unsigned short u16;
typedef unsigned int   u32;

__device__ __forceinline__ u16 f2h(float f) { return __builtin_bit_cast(u16, (_Float16)f); }
__device__ __forceinline__ u32 pk2(float f) { u32 h = f2h(f); return h | (h << 16); }
__device__ __forceinline__ f16x2 bch(u32 u) { return __builtin_bit_cast(f16x2, u); }

// ---------------------------------------------------------------------------
// KPREP (R5 version): lean skew-rotated LDS transpose.
// ---------------------------------------------------------------------------
__global__ __launch_bounds__(256) void kprep(const float* __restrict__ x, const float* __restrict__ wd,
                                             const float* __restrict__ wo, u16* __restrict__ xt,
                                             u16* __restrict__ wfrag, u16* __restrict__ wfrag2) {
  __shared__ float smem[8 * 576];               // 18 KB; transpose uses 9.2 KB as u32
  int blk = blockIdx.x;
  if (blk < 2048) {                             // ---- transpose to NHWC f16, 64 px ----
    int bg = blk >> 8;
    int p0 = (blk & 255) << 6;
    int pq = threadIdx.x & 15;                  // px quad: px = pq*4..+3
    int cs = threadIdx.x >> 4;                  // cpair seed 0..15
    const float* src = x + (size_t)bg * 64 * HW + p0 + pq * 4;
    u32* lds = (u32*)smem;                      // [px][36], col skew-rotated by px
    #pragma unroll
    for (int s = 0; s < 2; ++s) {
      int c2 = cs + 16 * s;                     // cpair index 0..31 (ch 2c2, 2c2+1)
      f32x4 lo = *(const f32x4*)(src + (size_t)(2 * c2 + 0) * HW);
      f32x4 hi = *(const f32x4*)(src + (size_t)(2 * c2 + 1) * HW);
      #pragma unroll
      for (int j = 0; j < 4; ++j) {
        int px = pq * 4 + j;
        u32 pkv = (u32)f2h(lo[j]) | ((u32)f2h(hi[j]) << 16);
        lds[px * 36 + ((c2 + px) & 31)] = pkv;  // skew: 2-way max
      }
    }
    __syncthreads();
    u16* dstb = xt + ((size_t)bg * HW + p0) * 64;
    #pragma unroll
    for (int r = 0; r < 2; ++r) {
      int e  = r * 256 + threadIdx.x;           // 0..511
      int px = e >> 3, c4 = e & 7;              // cpairs 4c4..4c4+3
      u32 w[4];
      #pragma unroll
      for (int m = 0; m < 4; ++m)
        w[m] = lds[px * 36 + ((4 * c4 + m + px) & 31)];
      *(uint4*)(dstb + (size_t)e * 8) = make_uint4(w[0], w[1], w[2], w[3]);
    }
  } else if (blk < 2176) {                      // ---- w_deform prepack (8 couts) ----
    int bb = blk - 2048;                        // 0..127
    int nh = bb & 31;                           // couts [nh*8, nh*8+8)
    int g  = bb >> 5;
    const float* src = wd + (size_t)(nh * 8) * 2304 + (size_t)g * 64 * 9;
    #pragma unroll
    for (int r = 0; r < 18; ++r) {
      int idx = threadIdx.x + 256 * r;          // 0..4607
      int cl  = idx / 576;
      int rem = idx - cl * 576;
      smem[cl * 576 + rem] = src[(size_t)cl * 2304 + rem];
    }
    __syncthreads();
    int nt = nh >> 1, nb = (nh & 1) * 8;
    #pragma unroll
    for (int r = 0; r < 18; ++r) {
      int o  = threadIdx.x + 256 * r;           // 0..4607
      int j  = o & 7;
      int n8 = (o >> 3) & 7;
      int q  = (o >> 6) & 3;
      int kcl = o >> 8;                         // t*2+half
      int t = kcl >> 1, half = kcl & 1;
      int cg = half * 32 + q * 8 + j;
      float v = smem[n8 * 576 + cg * 9 + t];
      int kc = (g * 9 + t) * 2 + half;
      int lane = q * 16 + nb + n8;
      wfrag[((size_t)(kc * 16 + nt) * 64 + lane) * 8 + j] = f2h(v);
    }
  } else {                                      // ---- w_offset prepack ----
    int e = (blk - 2176) * 256 + threadIdx.x;   // < 20480
    int j = e & 7;
    int lane = (e >> 3) & 63;
    int idx = e >> 9;
    int kc = idx / 5, nt = idx - 5 * kc;
    int n16 = lane & 15, q = lane >> 4;
    int oc = nt * 16 + n16;
    int c  = kc * 32 + q * 8 + j;
    float v = (oc < OFFC) ? wo[(size_t)oc * CIN + c] : 0.f;
    wfrag2[e] = f2h(v);
  }
}

// ---------------------------------------------------------------------------
// K2 (R8): 128-px tile per block, 16 waves, grid 256 = 1 block/CU.
//   Wave wv produces half-tile (sp=wv>>1, hp=wv&1), consumes cout slice
//   nt=wv (16 couts): acc[8] f32x4, 16 MFMA/tap. Gathers + B-frags
//   prefetched one phase ahead; __syncthreads barriers; XCD swizzle.
// ---------------------------------------------------------------------------
__device__ __forceinline__ void mkpre(float yy, float xx, int* ob, u32* wp) {
  float y0f = floorf(yy), x0f = floorf(xx);
  float fy = yy - y0f, fx = xx - x0f;
  int y0 = (int)y0f, x0 = (int)x0f;
  int y1 = y0 + 1, x1 = x0 + 1;
  float vy0 = (y0 >= 0 && y0 < Hh) ? 1.f : 0.f;
  float vy1 = (y1 >= 0 && y1 < Hh) ? 1.f : 0.f;
  float vx0 = (x0 >= 0 && x0 < Ww) ? 1.f : 0.f;
  float vx1 = (x1 >= 0 && x1 < Ww) ? 1.f : 0.f;
  wp[0] = pk2((1.f - fy) * (1.f - fx) * vy0 * vx0);   // zero-pad folded into weights
  wp[1] = pk2((1.f - fy) * fx * vy0 * vx1);
  wp[2] = pk2(fy * (1.f - fx) * vy1 * vx0);
  wp[3] = pk2(fy * fx * vy1 * vx1);
  int cy0 = min(max(y0, 0), Hh - 1), cy1 = min(max(y1, 0), Hh - 1);
  int cx0 = min(max(x0, 0), Ww - 1), cx1 = min(max(x1, 0), Ww - 1);
  ob[0] = (cy0 * Ww + cx0) << 7;                // byte offsets, 128 B pixel records
  ob[1] = (cy0 * Ww + cx1) << 7;
  ob[2] = (cy1 * Ww + cx0) << 7;
  ob[3] = (cy1 * Ww + cx1) << 7;
}

__device__ __forceinline__ uint4 bil16(const uint4* v, const u32* wp) {
  f16x2 W0 = bch(wp[0]), W1 = bch(wp[1]), W2 = bch(wp[2]), W3 = bch(wp[3]);
  uint4 r;
  { f16x2 s = bch(v[0].x) * W0 + bch(v[1].x) * W1 + bch(v[2].x) * W2 + bch(v[3].x) * W3; r.x = __builtin_bit_cast(u32, s); }
  { f16x2 s = bch(v[0].y) * W0 + bch(v[1].y) * W1 + bch(v[2].y) * W2 + bch(v[3].y) * W3; r.y = __builtin_bit_cast(u32, s); }
  { f16x2 s = bch(v[0].z) * W0 + bch(v[1].z) * W1 + bch(v[2].z) * W2 + bch(v[3].z) * W3; r.z = __builtin_bit_cast(u32, s); }
  { f16x2 s = bch(v[0].w) * W0 + bch(v[1].w) * W1 + bch(v[2].w) * W2 + bch(v[3].w) * W3; r.w = __builtin_bit_cast(u32, s); }
  return r;
}

__global__ __launch_bounds__(1024, 4) void k2(const u16* __restrict__ xt, const u16* __restrict__ wfrag2,
                                              const float* __restrict__ bo, const u16* __restrict__ wfrag,
                                              float* __restrict__ out) {
  __shared__ u16   astage[2 * 16 * 512];        // [buf][sp8*hp2][lane][8] = 32 KB
  __shared__ float offl[128 * 74];              // [px][oc] stride-74, 37.9 KB
  int tid  = threadIdx.x;
  int lane = tid & 63, n16 = lane & 15, q = (tid >> 4) & 3;
  int wv   = tid >> 6;                          // 0..15
  int sp   = wv >> 1;                           // produced px subtile (8)
  int hp   = wv & 1;                            // produced 32-ch half
  int blk  = blockIdx.x;
  int swz  = (blk & 7) * 32 + (blk >> 3);       // bijective XCD swizzle (256%8==0)
  int b  = swz >> 7;
  int p0 = (swz & 127) << 7;                    // 128-px tile = one image row
  int h  = p0 >> 7;
  const char* xtb = (const char*)xt + (size_t)b * 4 * HW * 128;
  float fh  = (float)h;
  float fxp = (float)(sp * 16 + n16);           // producer-pixel x (w0 == 0)
  int   chb = hp * 64 + q * 16;                 // byte offset within 128 B record
  int   pxl = sp * 16 + n16;

  f32x4 acc[8];
  #pragma unroll
  for (int mt = 0; mt < 8; ++mt) acc[mt] = (f32x4){0.f, 0.f, 0.f, 0.f};

  // ---- phase 0: waves 0-7 compute offset conv (128 px x 72 oc) -> offl ----
  if (wv < 8) {
    f32x4 oacc[5];
    #pragma unroll
    for (int nt = 0; nt < 5; ++nt) {
      int oc = nt * 16 + n16;
      float bv = (oc < OFFC) ? bo[oc] : 0.f;
      oacc[nt] = (f32x4){bv, bv, bv, bv};
    }
    #pragma unroll
    for (int kc = 0; kc < 8; ++kc) {
      int g = kc >> 1;
      f16x8 af = __builtin_bit_cast(f16x8, *(const uint4*)(xtb +
          ((size_t)(g * HW + p0 + wv * 16 + n16)) * 128 + (kc & 1) * 64 + q * 16));
      #pragma unroll
      for (int nt = 0; nt < 5; ++nt) {
        f16x8 bfo = __builtin_bit_cast(f16x8, *(const uint4*)(wfrag2 + (size_t)(((kc * 5 + nt) << 6) + lane) * 8));
        oacc[nt] = __builtin_amdgcn_mfma_f32_16x16x32_f16(af, bfo, oacc[nt], 0, 0, 0);
      }
    }
    #pragma unroll
    for (int nt = 0; nt < 5; ++nt) {
      int oc = nt * 16 + n16;
      if (oc < OFFC) {
        #pragma unroll
        for (int r = 0; r < 4; ++r)
          offl[(wv * 16 + q * 4 + r) * 74 + oc] = oacc[nt][r];
      }
    }
  }

  uint4 dA[4], dB[4];                           // ping-pong gather sets (const-indexed)
  u32   wpA[4], wpB[4];
  uint4 bfA[2], bfB[2];                         // ping-pong B-frag sets (nt = wv)

  auto bfld = [&](int gt, uint4* bf) {          // the two kc frags for tap gt, nt=wv
    const u16* wb = wfrag + ((size_t)((2 * gt) * 16 + wv) * 64 + lane) * 8;
    bf[0] = *(const uint4*)(wb);                // kc = 2gt   (ch half 0)
    bf[1] = *(const uint4*)(wb + 8192);         // kc = 2gt+1 (ch half 1)
  };

  bfld(0, bfA);                                 // tap0 B-frags (overlap offset conv)
  __syncthreads();                              // offl ready

  auto issue = [&](int gt, uint4* dd, u32* wpp) {
    float oy = offl[pxl * 74 + gt * 2];
    float ox = offl[pxl * 74 + gt * 2 + 1];
    int g = (gt * 57) >> 9;                     // gt/9
    int t = gt - g * 9;
    int i = (t * 683) >> 11;                    // t/3
    int j = t - i * 3;
    int ob[4];
    mkpre(fh + (float)(i - 1) + oy, fxp + (float)(j - 1) + ox, ob, wpp);
    const char* xg = xtb + (size_t)g * HW * 128;
    #pragma unroll
    for (int c = 0; c < 4; ++c)
      dd[c] = *(const uint4*)(xg + ob[c] + chb);
  };
  auto consume = [&](int slot, uint4* bf) {     // slot literal at call sites
    #pragma unroll
    for (int mt = 0; mt < 8; ++mt) {
      f16x8 af0 = __builtin_bit_cast(f16x8,
          *(const uint4*)&astage[(slot * 16 + mt * 2 + 0) * 512 + lane * 8]);
      acc[mt] = __builtin_amdgcn_mfma_f32_16x16x32_f16(af0, __builtin_bit_cast(f16x8, bf[0]), acc[mt], 0, 0, 0);
      f16x8 af1 = __builtin_bit_cast(f16x8,
          *(const uint4*)&astage[(slot * 16 + mt * 2 + 1) * 512 + lane * 8]);
      acc[mt] = __builtin_amdgcn_mfma_f32_16x16x32_f16(af1, __builtin_bit_cast(f16x8, bf[1]), acc[mt], 0, 0, 0);
    }
  };

  // ---- prologue: gt=0 -> dA, gt=1 -> dB, produce slot0 from dA ----
  issue(0, dA, wpA);
  issue(1, dB, wpB);
  *(uint4*)&astage[(0 * 16 + sp * 2 + hp) * 512 + lane * 8] = bil16(dA, wpA);
  __syncthreads();                              // slot0 ready

  // ---- main loop, x2 unrolled: per-tap phases, bf loads hoisted above
  //      gather issues (vmcnt in-order: B wait never drags gathers) ----
  #pragma unroll 1
  for (int gt = 0; gt < 36; gt += 2) {
    // even gt: stage gt+1 (dB) -> slot1; load bf(gt+1); issue gt+2; consume slot0
    *(uint4*)&astage[(1 * 16 + sp * 2 + hp) * 512 + lane * 8] = bil16(dB, wpB);
    bfld(gt + 1, bfB);                          // gt+1 <= 35 always
    if (gt + 2 < 36) issue(gt + 2, dA, wpA);
    consume(0, bfA);
    __syncthreads();
    // odd gt+1: stage gt+2 (dA) -> slot0; load bf(gt+2); issue gt+3; consume slot1
    if (gt + 2 < 36) {
      *(uint4*)&astage[(0 * 16 + sp * 2 + hp) * 512 + lane * 8] = bil16(dA, wpA);
      bfld(gt + 2, bfA);
      issue(gt + 3, dB, wpB);                   // gt+3 <= 35 here (gt <= 32)
    }
    consume(1, bfB);
    __syncthreads();
  }

  // ---- epilogue: px = p0 + mt*16 + q*4 + r, cout = wv*16 + n16; ReLU ----
  float* op = out + (size_t)b * COUT * HW + p0;
  int cout = wv * 16 + n16;
  #pragma unroll
  for (int mt = 0; mt < 8; ++mt) {
    f32x4 v = acc[mt];
    #pragma unroll
    for (int r = 0; r < 4; ++r) v[r] = fmaxf(v[r], 0.f);
    *(f32x4*)(op + (size_t)cout * HW + mt * 16 + q * 4) = v;
  }
}

// ---------------------------------------------------------------------------
extern "C" void kernel_launch(void* const* d_in, const int* in_sizes, int n_in,
                              void* d_out, int out_size, void* d_ws, size_t ws_size,
                              hipStream_t stream) {
  const float* x  = (const float*)d_in[0];
  const float* wo = (const float*)d_in[1];
  const float* bo = (const float*)d_in[2];
  const float* wd = (const float*)d_in[3];
  float* out = (float*)d_out;

  // ws: xt 16,777,216 | wfrag 1,179,648 | wfrag2 40,960
  u16* xtp    = (u16*)d_ws;
  u16* wfrag  = (u16*)((char*)d_ws + 16777216);
  u16* wfrag2 = (u16*)((char*)d_ws + 16777216 + 1179648);

  kprep<<<2256, 256, 0, stream>>>(x, wd, wo, xtp, wfrag, wfrag2);
  k2   <<<256, 1024, 0, stream>>>(xtp, wfrag2, bo, wfrag, out);
}